// Round 9
// baseline (247.602 us; speedup 1.0000x reference)
//
#include <hip/hip_runtime.h>

#define B_  4
#define S_  2048
#define D_  1024
#define N_  (B_*S_)
#define SCALE 0.03125f
#define NEGINF (-3.0e38f)

typedef unsigned short u16;
typedef __attribute__((ext_vector_type(8))) short short8;
typedef __attribute__((ext_vector_type(4))) float floatx4;

__device__ __forceinline__ u16 f2bf(float f) {           // RNE float->bf16
    unsigned int u = __float_as_uint(f);
    u += 0x7FFFu + ((u >> 16) & 1u);
    return (u16)(u >> 16);
}
__device__ __forceinline__ float bf2f(u16 h) {
    return __uint_as_float((unsigned int)h << 16);
}

__device__ __forceinline__ void gl_lds16(const void* g, void* l) {
    __builtin_amdgcn_global_load_lds(
        (const __attribute__((address_space(1))) unsigned int*)g,
        (__attribute__((address_space(3))) unsigned int*)l, 16, 0, 0);
}

// bijective chunked XCD swizzle (nwg % 8 == 0)
__device__ __forceinline__ int xcd_chunk(int bid, int nwg) {
    return (bid & 7) * (nwg >> 3) + (bid >> 3);
}

// ---------------- fused casts ----------------
__global__ __launch_bounds__(256) void cast_fused(const float* __restrict__ x,
                                                  const float* __restrict__ Wq, const float* __restrict__ Wk,
                                                  const float* __restrict__ Wv,
                                                  u16* __restrict__ xb, u16* __restrict__ Wqb,
                                                  u16* __restrict__ Wkb, u16* __restrict__ Wvt) {
    __shared__ float t[32][33];
    const int blk = blockIdx.x;
    if (blk < 5120) {
        const float* src; u16* dst; size_t i;
        if (blk < 4096)      { src = x;  dst = xb;  i = (size_t)blk * 2048; }
        else if (blk < 4608) { src = Wq; dst = Wqb; i = (size_t)(blk - 4096) * 2048; }
        else                 { src = Wk; dst = Wkb; i = (size_t)(blk - 4608) * 2048; }
        i += (size_t)threadIdx.x * 8;
        float4 a = *(const float4*)&src[i];
        float4 b = *(const float4*)&src[i + 4];
        short8 o;
        o[0]=f2bf(a.x); o[1]=f2bf(a.y); o[2]=f2bf(a.z); o[3]=f2bf(a.w);
        o[4]=f2bf(b.x); o[5]=f2bf(b.y); o[6]=f2bf(b.z); o[7]=f2bf(b.w);
        *(short8*)&dst[i] = o;
    } else {
        const int tb = blk - 5120;                 // 0..1023
        const int c = threadIdx.x & 31, r0 = threadIdx.x >> 5;
        const int i0 = (tb >> 5) * 32, j0 = (tb & 31) * 32;
#pragma unroll
        for (int rr = 0; rr < 4; ++rr)
            t[r0 + rr * 8][c] = Wv[(size_t)(i0 + r0 + rr * 8) * D_ + j0 + c];
        __syncthreads();
#pragma unroll
        for (int rr = 0; rr < 4; ++rr)
            Wvt[(size_t)(j0 + r0 + rr * 8) * D_ + i0 + c] = f2bf(t[c][r0 + rr * 8]);
    }
}

// =====================================================================================
// LDS layout: per buffer, per matrix, two k-half planes [kk][row][32].
// Within a row, 4 slots of 8 bf16; slot holds global k-octet (slot ^ ((row>>1)&3)).
// Swizzle on the GLOBAL source (gl_lds dest linear) + same involution on ds_read addr.
// =====================================================================================

// ================= 128x128 core: 4 waves (256 thr), single barrier/tile (r5-verified) =========
__device__ __forceinline__ void mfma_nt_128(const u16* __restrict__ A, int lda,
                                            const u16* __restrict__ Bp, int ldb,
                                            int m0, int n0, int kext,
                                            u16* Sh, floatx4 acc[4][4])
{
    const int tid  = threadIdx.x;          // 0..255
    const int lane = tid & 63;
    const int lr   = lane & 15, quad = lane >> 4;
    const int wm   = ((tid >> 6) & 1) * 64, wn = (tid >> 7) * 64;
    const int nt   = kext >> 6;

    auto stage8 = [&](int t) {
#pragma unroll
        for (int h = 0; h < 8; ++h) {
            const int kk = h >> 2, mat = (h >> 1) & 1, half = h & 1;
            const int idx = tid * 8;
            const int row = half * 64 + (idx >> 5);
            const int s   = (idx & 31) >> 3;
            const int gk  = (t << 6) + kk * 32 + ((s ^ ((row >> 1) & 3)) << 3);
            u16* dst = Sh + (t & 1) * 16384 + mat * 8192 + kk * 4096 + half * 2048 + idx;
            const u16* src = mat ? &Bp[(size_t)(n0 + row) * ldb + gk]
                                 : &A [(size_t)(m0 + row) * lda + gk];
            gl_lds16(src, dst);
        }
    };

    stage8(0);
    for (int t = 0; t < nt; ++t) {
        asm volatile("s_waitcnt vmcnt(0)" ::: "memory");
        __builtin_amdgcn_s_barrier();
        if (t + 1 < nt) stage8(t + 1);
        const u16* buf = Sh + (t & 1) * 16384;
#pragma unroll
        for (int kk = 0; kk < 2; ++kk) {
            short8 af[4], bf[4];
#pragma unroll
            for (int i = 0; i < 4; ++i) {
                const int ar = wm + i * 16 + lr;
                af[i] = *(const short8*)&buf[kk * 4096 + ar * 32 + ((quad ^ ((ar >> 1) & 3)) << 3)];
                const int br = wn + i * 16 + lr;
                bf[i] = *(const short8*)&buf[8192 + kk * 4096 + br * 32 + ((quad ^ ((br >> 1) & 3)) << 3)];
            }
            __builtin_amdgcn_s_setprio(1);
#pragma unroll
            for (int i = 0; i < 4; ++i)
#pragma unroll
                for (int j = 0; j < 4; ++j)
                    acc[i][j] = __builtin_amdgcn_mfma_f32_16x16x32_bf16(af[i], bf[j], acc[i][j], 0, 0, 0);
            __builtin_amdgcn_s_setprio(0);
        }
    }
}

#define EPI_VARS                                              \
    const int lane = threadIdx.x & 63;                        \
    const int lr = lane & 15, quad = lane >> 4;               \
    const int wm = ((threadIdx.x >> 6) & 1) * 64, wn = (threadIdx.x >> 7) * 64;

// ================= 256x256 core: 8 waves (2Mx4N), SAFE 4-phase, counted vmcnt (r7-verified) =====
__device__ __forceinline__ void mfma_nt_256(const u16* __restrict__ A, int lda,
                                            const u16* __restrict__ Bp, int ldb,
                                            int m0, int n0, int kext,
                                            u16* Sh, floatx4 acc[8][4])
{
    const int tid  = threadIdx.x;          // 0..511
    const int lane = tid & 63;
    const int lr   = lane & 15, quad = lane >> 4;
    const int wr   = (tid >> 8) & 1, wc = (tid >> 6) & 3;
    const int nt   = kext >> 6;

    auto stage = [&](int t, int mat, int kk) {
#pragma unroll
        for (int pass = 0; pass < 2; ++pass) {
            const int idx = pass * 4096 + tid * 8;
            const int row = idx >> 5;
            const int s   = (idx & 31) >> 3;
            const int gk  = (t << 6) + kk * 32 + ((s ^ ((row >> 1) & 3)) << 3);
            u16* dst = Sh + (t & 1) * 32768 + mat * 16384 + kk * 8192 + idx;
            const u16* src = mat ? &Bp[(size_t)(n0 + row) * ldb + gk]
                                 : &A [(size_t)(m0 + row) * lda + gk];
            gl_lds16(src, dst);
        }
    };

    stage(0, 0, 0); stage(0, 1, 0); stage(0, 0, 1); stage(0, 1, 1);
    asm volatile("s_waitcnt vmcnt(4)" ::: "memory");
    __builtin_amdgcn_s_barrier();

    for (int t = 0; t < nt; ++t) {
        const u16* buf = Sh + (t & 1) * 32768;
        const bool pf = (t + 1 < nt);
        short8 af[4], bf[4];

#pragma unroll
        for (int kk = 0; kk < 2; ++kk) {
            const int kb = kk * 8192;

            // ---- phase (kk, mh0) ----
#pragma unroll
            for (int i = 0; i < 4; ++i) {
                const int ar = wr * 128 + i * 16 + lr;
                af[i] = *(const short8*)&buf[kb + ar * 32 + ((quad ^ ((ar >> 1) & 3)) << 3)];
            }
#pragma unroll
            for (int j = 0; j < 4; ++j) {
                const int br = wc * 64 + j * 16 + lr;
                bf[j] = *(const short8*)&buf[16384 + kb + br * 32 + ((quad ^ ((br >> 1) & 3)) << 3)];
            }
            if (pf) stage(t + 1, 0, kk);
            __builtin_amdgcn_s_barrier();
            asm volatile("s_waitcnt lgkmcnt(0)" ::: "memory");
            __builtin_amdgcn_s_setprio(1);
#pragma unroll
            for (int i = 0; i < 4; ++i)
#pragma unroll
                for (int j = 0; j < 4; ++j)
                    acc[i][j] = __builtin_amdgcn_mfma_f32_16x16x32_bf16(af[i], bf[j], acc[i][j], 0, 0, 0);
            __builtin_amdgcn_s_setprio(0);
            __builtin_amdgcn_s_barrier();

            // ---- phase (kk, mh1) ----
#pragma unroll
            for (int i = 0; i < 4; ++i) {
                const int ar = wr * 128 + 64 + i * 16 + lr;
                af[i] = *(const short8*)&buf[kb + ar * 32 + ((quad ^ ((ar >> 1) & 3)) << 3)];
            }
            if (pf) stage(t + 1, 1, kk);
            if (kk == 0) {
                if (pf) asm volatile("s_waitcnt vmcnt(4)" ::: "memory");
                else    asm volatile("s_waitcnt vmcnt(0)" ::: "memory");
            } else if (pf) {
                asm volatile("s_waitcnt vmcnt(4)" ::: "memory");
            }
            __builtin_amdgcn_s_barrier();
            asm volatile("s_waitcnt lgkmcnt(0)" ::: "memory");
            __builtin_amdgcn_s_setprio(1);
#pragma unroll
            for (int i = 0; i < 4; ++i)
#pragma unroll
                for (int j = 0; j < 4; ++j)
                    acc[4 + i][j] = __builtin_amdgcn_mfma_f32_16x16x32_bf16(af[i], bf[j], acc[4 + i][j], 0, 0, 0);
            __builtin_amdgcn_s_setprio(0);
            __builtin_amdgcn_s_barrier();
        }
    }
}

#define EPI256_VARS                                           \
    const int lane = threadIdx.x & 63;                        \
    const int lr = lane & 15, quad = lane >> 4;               \
    const int wr = (threadIdx.x >> 8) & 1, wc = (threadIdx.x >> 6) & 3;

// ========== PV core: 128x128, 8 waves, wave tile 32x64, with in-register exp transform ==========
// A = Sc (bf16 scores, scaled+masked). af rows get p = exp(s - M_row) applied before MFMA;
// 1/sum is folded into the f32 epilogue (flash factorization). Masked s=NEGINF -> p=0.
__device__ __forceinline__ void pv_loop(const u16* __restrict__ A, int lda,
                                        const u16* __restrict__ Bp, int ldb,
                                        int m0, int n0, int kext,
                                        u16* Sh, float mA, float mB, floatx4 acc[2][4])
{
    const int tid  = threadIdx.x;          // 0..511
    const int lane = tid & 63;
    const int lr   = lane & 15, quad = lane >> 4;
    const int wid  = tid >> 6;
    const int wm   = (wid >> 1) * 32;
    const int wn   = (wid & 1) * 64;
    const int nt   = kext >> 6;

    auto stage4 = [&](int t) {
#pragma unroll
        for (int h = 0; h < 4; ++h) {
            const int kk = h >> 1, mat = h & 1;
            const int idx = tid * 8;
            const int row = idx >> 5;
            const int s   = (idx & 31) >> 3;
            const int gk  = (t << 6) + kk * 32 + ((s ^ ((row >> 1) & 3)) << 3);
            u16* dst = Sh + (t & 1) * 16384 + mat * 8192 + kk * 4096 + idx;
            const u16* src = mat ? &Bp[(size_t)(n0 + row) * ldb + gk]
                                 : &A [(size_t)(m0 + row) * lda + gk];
            gl_lds16(src, dst);
        }
    };

    auto xf = [&](short8 a, float m) {     // p = exp(s - m), bf16
        short8 o;
#pragma unroll
        for (int e = 0; e < 8; ++e)
            o[e] = (short)f2bf(__expf(bf2f((u16)a[e]) - m));
        return o;
    };

    stage4(0);
    for (int t = 0; t < nt; ++t) {
        asm volatile("s_waitcnt vmcnt(0)" ::: "memory");
        __builtin_amdgcn_s_barrier();
        if (t + 1 < nt) stage4(t + 1);
        const u16* buf = Sh + (t & 1) * 16384;
#pragma unroll
        for (int kk = 0; kk < 2; ++kk) {
            short8 af[2], bf[4];
#pragma unroll
            for (int i = 0; i < 2; ++i) {
                const int ar = wm + i * 16 + lr;
                af[i] = *(const short8*)&buf[kk * 4096 + ar * 32 + ((quad ^ ((ar >> 1) & 3)) << 3)];
            }
#pragma unroll
            for (int j = 0; j < 4; ++j) {
                const int br = wn + j * 16 + lr;
                bf[j] = *(const short8*)&buf[8192 + kk * 4096 + br * 32 + ((quad ^ ((br >> 1) & 3)) << 3)];
            }
            af[0] = xf(af[0], mA);
            af[1] = xf(af[1], mB);
            __builtin_amdgcn_s_setprio(1);
#pragma unroll
            for (int i = 0; i < 2; ++i)
#pragma unroll
                for (int j = 0; j < 4; ++j)
                    acc[i][j] = __builtin_amdgcn_mfma_f32_16x16x32_bf16(af[i], bf[j], acc[i][j], 0, 0, 0);
            __builtin_amdgcn_s_setprio(0);
        }
    }
}

// ---------------- K1: Mt = Wk *NT* Wq ----------------
__global__ __launch_bounds__(256) void mt_mfma(const u16* __restrict__ Wkb, const u16* __restrict__ Wqb,
                                               u16* __restrict__ Mt)
{
    __shared__ u16 Sh[32768];
    const int m0 = blockIdx.y * 128, n0 = blockIdx.x * 128;
    floatx4 acc[4][4];
#pragma unroll
    for (int i = 0; i < 4; ++i)
#pragma unroll
        for (int j = 0; j < 4; ++j) acc[i][j] = (floatx4){0.f, 0.f, 0.f, 0.f};
    mfma_nt_128(Wkb, D_, Wqb, D_, m0, n0, D_, Sh, acc);

    EPI_VARS
#pragma unroll
    for (int i = 0; i < 4; ++i)
#pragma unroll
        for (int j = 0; j < 4; ++j)
#pragma unroll
            for (int r = 0; r < 4; ++r)
                Mt[(size_t)(m0 + wm + i * 16 + quad * 4 + r) * D_ + n0 + wn + j * 16 + lr] = f2bf(acc[i][j][r]);
}

// ---------------- K2+K3 merged on 256^2 core: 256 blocks = 1/CU (r7-verified) ----------------
__global__ __launch_bounds__(512, 2) void yv_mfma(const u16* __restrict__ xb, const u16* __restrict__ Mt,
                                                  const u16* __restrict__ Wvt,
                                                  u16* __restrict__ Y, u16* __restrict__ Vt)
{
    __shared__ u16 Sh[65536];
    const int lid = xcd_chunk(blockIdx.x, 256);
    floatx4 acc[8][4];
#pragma unroll
    for (int i = 0; i < 8; ++i)
#pragma unroll
        for (int j = 0; j < 4; ++j) acc[i][j] = (floatx4){0.f, 0.f, 0.f, 0.f};

    if (lid < 128) {
        const int m0 = (lid >> 2) * 256, n0 = (lid & 3) * 256;
        mfma_nt_256(xb, D_, Mt, D_, m0, n0, D_, Sh, acc);
        EPI256_VARS
#pragma unroll
        for (int i = 0; i < 8; ++i)
#pragma unroll
            for (int j = 0; j < 4; ++j)
#pragma unroll
                for (int r = 0; r < 4; ++r)
                    Y[(size_t)(m0 + wr * 128 + i * 16 + quad * 4 + r) * D_ + n0 + wc * 64 + j * 16 + lr]
                        = f2bf(acc[i][j][r]);
    } else {
        const int v = lid - 128;
        const int b = v >> 5;
        const int mloc = ((v >> 2) & 7) * 256;
        const int n0 = (v & 3) * 256;
        const int m0 = b * S_ + mloc;
        u16* Vb = Vt + (size_t)b * D_ * S_;
        mfma_nt_256(xb, D_, Wvt, D_, m0, n0, D_, Sh, acc);
        EPI256_VARS
#pragma unroll
        for (int i = 0; i < 8; ++i)
#pragma unroll
            for (int j = 0; j < 4; ++j) {
                const int ee = n0 + wc * 64 + j * 16 + lr;
                const int s4 = mloc + wr * 128 + i * 16 + quad * 4;
                ushort4 o;
                o.x = f2bf(acc[i][j][0]); o.y = f2bf(acc[i][j][1]);
                o.z = f2bf(acc[i][j][2]); o.w = f2bf(acc[i][j][3]);
                *(ushort4*)&Vb[(size_t)ee * S_ + s4] = o;
            }
    }
}

// ---------------- K4: Sc + per-(row, kt256) softmax partials (max, expsum) ----------------
__global__ __launch_bounds__(512, 2) void scores_mfma(const u16* __restrict__ Y, const u16* __restrict__ xb,
                                                      u16* __restrict__ Sc,
                                                      float* __restrict__ Pm, float* __restrict__ Ps)
{
    __shared__ u16 Sh[65536];
    const int lid = xcd_chunk(blockIdx.x, 144);
    const int bb = lid / 36;
    const int t = lid - bb * 36;
    int qt = 0;
    while ((qt + 1) * (qt + 2) / 2 <= t) ++qt;
    const int kt = t - qt * (qt + 1) / 2;

    const u16* A  = Y  + (size_t)bb * S_ * D_;
    const u16* Bp = xb + (size_t)bb * S_ * D_;
    u16* Sb = Sc + (size_t)bb * S_ * S_;
    const int m0 = qt * 256, n0 = kt * 256;
    floatx4 acc[8][4];
#pragma unroll
    for (int i = 0; i < 8; ++i)
#pragma unroll
        for (int j = 0; j < 4; ++j) acc[i][j] = (floatx4){0.f, 0.f, 0.f, 0.f};
    mfma_nt_256(A, D_, Bp, D_, m0, n0, D_, Sh, acc);

    EPI256_VARS
    const int tid = threadIdx.x;
    const int kt256 = n0 >> 8;
    float* redM = (float*)Sh;              // [4][256] (aliases staging, post-barrier)
    float* redS = redM + 1024;             // [4][256]

    // pass 1: Sc store + per-row tile max (shfl over 16-lane lr group, LDS over wc)
#pragma unroll
    for (int i = 0; i < 8; ++i)
#pragma unroll
        for (int r = 0; r < 4; ++r) {
            const int rl   = wr * 128 + i * 16 + quad * 4 + r;
            const int grow = m0 + rl;
            float vm = NEGINF;
#pragma unroll
            for (int j = 0; j < 4; ++j) {
                const int gcol = n0 + wc * 64 + j * 16 + lr;
                const float v = (gcol <= grow) ? acc[i][j][r] * SCALE : NEGINF;
                Sb[(size_t)grow * S_ + gcol] = f2bf(v);
                vm = fmaxf(vm, v);
            }
#pragma unroll
            for (int off = 1; off < 16; off <<= 1) vm = fmaxf(vm, __shfl_xor(vm, off, 64));
            if (lr == 0) redM[wc * 256 + rl] = vm;
        }
    __syncthreads();
    if (tid < 256) {
        const float m4 = fmaxf(fmaxf(redM[tid], redM[256 + tid]),
                               fmaxf(redM[512 + tid], redM[768 + tid]));
        redM[tid] = m4;
        Pm[((size_t)bb * 2048 + m0 + tid) * 8 + kt256] = m4;
    }
    __syncthreads();
    // pass 2: expsum vs tile max (explicit mask predicate; never exp(NEGINF-NEGINF))
#pragma unroll
    for (int i = 0; i < 8; ++i)
#pragma unroll
        for (int r = 0; r < 4; ++r) {
            const int rl   = wr * 128 + i * 16 + quad * 4 + r;
            const int grow = m0 + rl;
            const float m = redM[rl];
            float s = 0.f;
#pragma unroll
            for (int j = 0; j < 4; ++j) {
                const int gcol = n0 + wc * 64 + j * 16 + lr;
                if (gcol <= grow) s += __expf(acc[i][j][r] * SCALE - m);
            }
#pragma unroll
            for (int off = 1; off < 16; off <<= 1) s += __shfl_xor(s, off, 64);
            if (lr == 0) redS[wc * 256 + rl] = s;
        }
    __syncthreads();
    if (tid < 256)
        Ps[((size_t)bb * 2048 + m0 + tid) * 8 + kt256] =
            redS[tid] + redS[256 + tid] + redS[512 + tid] + redS[768 + tid];
}

// ---------------- K5: fused softmax+PV: O = softmax(Sc) Vt^T (512 blocks, 2/CU) ----------------
// Prologue: combine per-row partials (log-sum-exp over kt256) into Mtab/Itab.
// K-loop: A = Sc with exp(s - M) applied in-register. Epilogue: O = acc * Itab[row].
__global__ __launch_bounds__(512, 2) void pv_mfma(const u16* __restrict__ Sc, const u16* __restrict__ Vt,
                                                  const float* __restrict__ Pm, const float* __restrict__ Ps,
                                                  float* __restrict__ O)
{
    __shared__ u16 Sh[32768];                  // 64 KiB staging
    __shared__ float Mtab[128], Itab[128];
    const int lid = xcd_chunk(blockIdx.x, 512);
    const int s  = lid >> 5;                   // 0..15
    const int be = lid & 31;
    const int b  = be >> 3, et = be & 7;
    const int qt = (s & 1) ? 15 - (s >> 1) : (s >> 1);
    const int m0 = qt * 128, n0 = et * 128;
    const int kext = (qt + 1) * 128;
    const u16* A  = Sc + (size_t)b * S_ * S_;
    const u16* Bp = Vt + (size_t)b * D_ * S_;

    const int tid = threadIdx.x;
    if (tid < 128) {
        const int g = m0 + tid;
        const int nkt = (g >> 8) + 1;          // kt256 count for this row
        const float* pm = Pm + ((size_t)b * 2048 + g) * 8;
        const float* ps = Ps + ((size_t)b * 2048 + g) * 8;
        float M = NEGINF;
        for (int k = 0; k < nkt; ++k) M = fmaxf(M, pm[k]);
        float Ssum = 0.f;
        for (int k = 0; k < nkt; ++k) Ssum += ps[k] * __expf(pm[k] - M);
        Mtab[tid] = M;
        Itab[tid] = 1.0f / Ssum;
    }
    __syncthreads();

    const int lane = tid & 63;
    const int lr = lane & 15, quad = lane >> 4;
    const int wid = tid >> 6;
    const int wm = (wid >> 1) * 32, wn = (wid & 1) * 64;
    const float mA = Mtab[wm + lr];            // af[0] row max
    const float mB = Mtab[wm + 16 + lr];       // af[1] row max

    floatx4 acc[2][4];
#pragma unroll
    for (int i = 0; i < 2; ++i)
#pragma unroll
        for (int j = 0; j < 4; ++j) acc[i][j] = (floatx4){0.f, 0.f, 0.f, 0.f};
    pv_loop(A, S_, Bp, S_, m0, n0, kext, Sh, mA, mB, acc);

#pragma unroll
    for (int i = 0; i < 2; ++i)
#pragma unroll
        for (int r = 0; r < 4; ++r) {
            const int rl = wm + i * 16 + quad * 4 + r;
            const float inv = Itab[rl];
            const int grow = m0 + rl;
#pragma unroll
            for (int j = 0; j < 4; ++j)
                O[((size_t)b * S_ + grow) * D_ + n0 + wn + j * 16 + lr] = acc[i][j][r] * inv;
        }
}

extern "C" void kernel_launch(void* const* d_in, const int* in_sizes, int n_in,
                              void* d_out, int out_size, void* d_ws, size_t ws_size,
                              hipStream_t stream) {
    const float* x  = (const float*)d_in[0];
    const float* Wq = (const float*)d_in[1];
    const float* Wk = (const float*)d_in[2];
    const float* Wv = (const float*)d_in[3];
    float* out = (float*)d_out;
    char* w = (char*)d_ws;

    u16* xb  = (u16*)(w);                    // 16.8 MB
    u16* Wqb = (u16*)(w + 16777216);         //  2 MB
    u16* Wkb = (u16*)(w + 18874368);         //  2 MB
    u16* Wvt = (u16*)(w + 20971520);         //  2 MB
    u16* Mt  = (u16*)(w + 23068672);         //  2 MB
    u16* Y   = (u16*)(w + 25165824);         // 16.8 MB
    u16* Vt  = (u16*)(w + 41943040);         // 16.8 MB
    u16* Sc  = (u16*)(w + 58720256);         // 33.5 MB
    float* Pm = (float*)(w + 92274688);      // 256 KB partial row maxes [b][row][8]
    float* Ps = (float*)(w + 92536832);      // 256 KB partial exp sums  [b][row][8]

    cast_fused <<<dim3(6144),   256, 0, stream>>>(x, Wq, Wk, Wv, xb, Wqb, Wkb, Wvt);
    mt_mfma    <<<dim3(8, 8),   256, 0, stream>>>(Wkb, Wqb, Mt);
    yv_mfma    <<<dim3(256),    512, 0, stream>>>(xb, Mt, Wvt, Y, Vt);
    scores_mfma<<<dim3(144),    512, 0, stream>>>(Y, xb, Sc, Pm, Ps);
    pv_mfma    <<<dim3(512),    512, 0, stream>>>(Sc, Vt, Pm, Ps, out);
}

// Round 10
// 211.160 us; speedup vs baseline: 1.1726x; 1.1726x over previous
//
#include <hip/hip_runtime.h>

#define B_  4
#define S_  2048
#define D_  1024
#define N_  (B_*S_)
#define SCALE 0.03125f
#define NEGINF (-3.0e38f)

typedef unsigned short u16;
typedef __attribute__((ext_vector_type(8))) short short8;
typedef __attribute__((ext_vector_type(4))) float floatx4;

__device__ __forceinline__ u16 f2bf(float f) {           // RNE float->bf16
    unsigned int u = __float_as_uint(f);
    u += 0x7FFFu + ((u >> 16) & 1u);
    return (u16)(u >> 16);
}
__device__ __forceinline__ float bf2f(u16 h) {
    return __uint_as_float((unsigned int)h << 16);
}

__device__ __forceinline__ void gl_lds16(const void* g, void* l) {
    __builtin_amdgcn_global_load_lds(
        (const __attribute__((address_space(1))) unsigned int*)g,
        (__attribute__((address_space(3))) unsigned int*)l, 16, 0, 0);
}

// bijective chunked XCD swizzle (nwg % 8 == 0)
__device__ __forceinline__ int xcd_chunk(int bid, int nwg) {
    return (bid & 7) * (nwg >> 3) + (bid >> 3);
}

// ---------------- fused casts ----------------
__global__ __launch_bounds__(256) void cast_fused(const float* __restrict__ x,
                                                  const float* __restrict__ Wq, const float* __restrict__ Wk,
                                                  const float* __restrict__ Wv,
                                                  u16* __restrict__ xb, u16* __restrict__ Wqb,
                                                  u16* __restrict__ Wkb, u16* __restrict__ Wvt) {
    __shared__ float t[32][33];
    const int blk = blockIdx.x;
    if (blk < 5120) {
        const float* src; u16* dst; size_t i;
        if (blk < 4096)      { src = x;  dst = xb;  i = (size_t)blk * 2048; }
        else if (blk < 4608) { src = Wq; dst = Wqb; i = (size_t)(blk - 4096) * 2048; }
        else                 { src = Wk; dst = Wkb; i = (size_t)(blk - 4608) * 2048; }
        i += (size_t)threadIdx.x * 8;
        float4 a = *(const float4*)&src[i];
        float4 b = *(const float4*)&src[i + 4];
        short8 o;
        o[0]=f2bf(a.x); o[1]=f2bf(a.y); o[2]=f2bf(a.z); o[3]=f2bf(a.w);
        o[4]=f2bf(b.x); o[5]=f2bf(b.y); o[6]=f2bf(b.z); o[7]=f2bf(b.w);
        *(short8*)&dst[i] = o;
    } else {
        const int tb = blk - 5120;                 // 0..1023
        const int c = threadIdx.x & 31, r0 = threadIdx.x >> 5;
        const int i0 = (tb >> 5) * 32, j0 = (tb & 31) * 32;
#pragma unroll
        for (int rr = 0; rr < 4; ++rr)
            t[r0 + rr * 8][c] = Wv[(size_t)(i0 + r0 + rr * 8) * D_ + j0 + c];
        __syncthreads();
#pragma unroll
        for (int rr = 0; rr < 4; ++rr)
            Wvt[(size_t)(j0 + r0 + rr * 8) * D_ + i0 + c] = f2bf(t[c][r0 + rr * 8]);
    }
}

// =====================================================================================
// LDS layout: per buffer, per matrix, two k-half planes [kk][row][32].
// Within a row, 4 slots of 8 bf16; slot holds global k-octet (slot ^ ((row>>1)&3)).
// Swizzle on the GLOBAL source (gl_lds dest linear) + same involution on ds_read addr.
// =====================================================================================

// ================= 128x128 core: 4 waves (256 thr), single barrier/tile (r5-verified) =========
__device__ __forceinline__ void mfma_nt_128(const u16* __restrict__ A, int lda,
                                            const u16* __restrict__ Bp, int ldb,
                                            int m0, int n0, int kext,
                                            u16* Sh, floatx4 acc[4][4])
{
    const int tid  = threadIdx.x;          // 0..255
    const int lane = tid & 63;
    const int lr   = lane & 15, quad = lane >> 4;
    const int wm   = ((tid >> 6) & 1) * 64, wn = (tid >> 7) * 64;
    const int nt   = kext >> 6;

    auto stage8 = [&](int t) {
#pragma unroll
        for (int h = 0; h < 8; ++h) {
            const int kk = h >> 2, mat = (h >> 1) & 1, half = h & 1;
            const int idx = tid * 8;
            const int row = half * 64 + (idx >> 5);
            const int s   = (idx & 31) >> 3;
            const int gk  = (t << 6) + kk * 32 + ((s ^ ((row >> 1) & 3)) << 3);
            u16* dst = Sh + (t & 1) * 16384 + mat * 8192 + kk * 4096 + half * 2048 + idx;
            const u16* src = mat ? &Bp[(size_t)(n0 + row) * ldb + gk]
                                 : &A [(size_t)(m0 + row) * lda + gk];
            gl_lds16(src, dst);
        }
    };

    stage8(0);
    for (int t = 0; t < nt; ++t) {
        asm volatile("s_waitcnt vmcnt(0)" ::: "memory");
        __builtin_amdgcn_s_barrier();
        if (t + 1 < nt) stage8(t + 1);
        const u16* buf = Sh + (t & 1) * 16384;
#pragma unroll
        for (int kk = 0; kk < 2; ++kk) {
            short8 af[4], bf[4];
#pragma unroll
            for (int i = 0; i < 4; ++i) {
                const int ar = wm + i * 16 + lr;
                af[i] = *(const short8*)&buf[kk * 4096 + ar * 32 + ((quad ^ ((ar >> 1) & 3)) << 3)];
                const int br = wn + i * 16 + lr;
                bf[i] = *(const short8*)&buf[8192 + kk * 4096 + br * 32 + ((quad ^ ((br >> 1) & 3)) << 3)];
            }
            __builtin_amdgcn_s_setprio(1);
#pragma unroll
            for (int i = 0; i < 4; ++i)
#pragma unroll
                for (int j = 0; j < 4; ++j)
                    acc[i][j] = __builtin_amdgcn_mfma_f32_16x16x32_bf16(af[i], bf[j], acc[i][j], 0, 0, 0);
            __builtin_amdgcn_s_setprio(0);
        }
    }
}

#define EPI_VARS                                              \
    const int lane = threadIdx.x & 63;                        \
    const int lr = lane & 15, quad = lane >> 4;               \
    const int wm = ((threadIdx.x >> 6) & 1) * 64, wn = (threadIdx.x >> 7) * 64;

// ========== 128x128 core, 8 waves (512 thr): wave tile 32x64, 64 KiB LDS (r4-r8-verified) ==========
__device__ __forceinline__ void mfma_nt_128w8(const u16* __restrict__ A, int lda,
                                              const u16* __restrict__ Bp, int ldb,
                                              int m0, int n0, int kext,
                                              u16* Sh, floatx4 acc[2][4])
{
    const int tid  = threadIdx.x;          // 0..511
    const int lane = tid & 63;
    const int lr   = lane & 15, quad = lane >> 4;
    const int wid  = tid >> 6;             // 0..7
    const int wm   = (wid >> 1) * 32;      // 0,32,64,96
    const int wn   = (wid & 1) * 64;       // 0,64
    const int nt   = kext >> 6;

    auto stage4 = [&](int t) {
#pragma unroll
        for (int h = 0; h < 4; ++h) {
            const int kk = h >> 1, mat = h & 1;
            const int idx = tid * 8;       // 0..4095 -> full 128x32 plane
            const int row = idx >> 5;
            const int s   = (idx & 31) >> 3;
            const int gk  = (t << 6) + kk * 32 + ((s ^ ((row >> 1) & 3)) << 3);
            u16* dst = Sh + (t & 1) * 16384 + mat * 8192 + kk * 4096 + idx;
            const u16* src = mat ? &Bp[(size_t)(n0 + row) * ldb + gk]
                                 : &A [(size_t)(m0 + row) * lda + gk];
            gl_lds16(src, dst);
        }
    };

    stage4(0);
    for (int t = 0; t < nt; ++t) {
        asm volatile("s_waitcnt vmcnt(0)" ::: "memory");
        __builtin_amdgcn_s_barrier();
        if (t + 1 < nt) stage4(t + 1);
        const u16* buf = Sh + (t & 1) * 16384;
#pragma unroll
        for (int kk = 0; kk < 2; ++kk) {
            short8 af[2], bf[4];
#pragma unroll
            for (int i = 0; i < 2; ++i) {
                const int ar = wm + i * 16 + lr;
                af[i] = *(const short8*)&buf[kk * 4096 + ar * 32 + ((quad ^ ((ar >> 1) & 3)) << 3)];
            }
#pragma unroll
            for (int j = 0; j < 4; ++j) {
                const int br = wn + j * 16 + lr;
                bf[j] = *(const short8*)&buf[8192 + kk * 4096 + br * 32 + ((quad ^ ((br >> 1) & 3)) << 3)];
            }
            __builtin_amdgcn_s_setprio(1);
#pragma unroll
            for (int i = 0; i < 2; ++i)
#pragma unroll
                for (int j = 0; j < 4; ++j)
                    acc[i][j] = __builtin_amdgcn_mfma_f32_16x16x32_bf16(af[i], bf[j], acc[i][j], 0, 0, 0);
            __builtin_amdgcn_s_setprio(0);
        }
    }
}

#define EPIW8_VARS                                            \
    const int lane = threadIdx.x & 63;                        \
    const int lr = lane & 15, quad = lane >> 4;               \
    const int wid = threadIdx.x >> 6;                         \
    const int wm = (wid >> 1) * 32, wn = (wid & 1) * 64;

// ================= 256x256 core: 8 waves (2Mx4N), SAFE 4-phase, counted vmcnt (r7-verified) =====
__device__ __forceinline__ void mfma_nt_256(const u16* __restrict__ A, int lda,
                                            const u16* __restrict__ Bp, int ldb,
                                            int m0, int n0, int kext,
                                            u16* Sh, floatx4 acc[8][4])
{
    const int tid  = threadIdx.x;          // 0..511
    const int lane = tid & 63;
    const int lr   = lane & 15, quad = lane >> 4;
    const int wr   = (tid >> 8) & 1, wc = (tid >> 6) & 3;
    const int nt   = kext >> 6;

    auto stage = [&](int t, int mat, int kk) {
#pragma unroll
        for (int pass = 0; pass < 2; ++pass) {
            const int idx = pass * 4096 + tid * 8;
            const int row = idx >> 5;
            const int s   = (idx & 31) >> 3;
            const int gk  = (t << 6) + kk * 32 + ((s ^ ((row >> 1) & 3)) << 3);
            u16* dst = Sh + (t & 1) * 32768 + mat * 16384 + kk * 8192 + idx;
            const u16* src = mat ? &Bp[(size_t)(n0 + row) * ldb + gk]
                                 : &A [(size_t)(m0 + row) * lda + gk];
            gl_lds16(src, dst);
        }
    };

    stage(0, 0, 0); stage(0, 1, 0); stage(0, 0, 1); stage(0, 1, 1);
    asm volatile("s_waitcnt vmcnt(4)" ::: "memory");
    __builtin_amdgcn_s_barrier();

    for (int t = 0; t < nt; ++t) {
        const u16* buf = Sh + (t & 1) * 32768;
        const bool pf = (t + 1 < nt);
        short8 af[4], bf[4];

#pragma unroll
        for (int kk = 0; kk < 2; ++kk) {
            const int kb = kk * 8192;

            // ---- phase (kk, mh0) ----
#pragma unroll
            for (int i = 0; i < 4; ++i) {
                const int ar = wr * 128 + i * 16 + lr;
                af[i] = *(const short8*)&buf[kb + ar * 32 + ((quad ^ ((ar >> 1) & 3)) << 3)];
            }
#pragma unroll
            for (int j = 0; j < 4; ++j) {
                const int br = wc * 64 + j * 16 + lr;
                bf[j] = *(const short8*)&buf[16384 + kb + br * 32 + ((quad ^ ((br >> 1) & 3)) << 3)];
            }
            if (pf) stage(t + 1, 0, kk);
            __builtin_amdgcn_s_barrier();
            asm volatile("s_waitcnt lgkmcnt(0)" ::: "memory");
            __builtin_amdgcn_s_setprio(1);
#pragma unroll
            for (int i = 0; i < 4; ++i)
#pragma unroll
                for (int j = 0; j < 4; ++j)
                    acc[i][j] = __builtin_amdgcn_mfma_f32_16x16x32_bf16(af[i], bf[j], acc[i][j], 0, 0, 0);
            __builtin_amdgcn_s_setprio(0);
            __builtin_amdgcn_s_barrier();

            // ---- phase (kk, mh1) ----
#pragma unroll
            for (int i = 0; i < 4; ++i) {
                const int ar = wr * 128 + 64 + i * 16 + lr;
                af[i] = *(const short8*)&buf[kb + ar * 32 + ((quad ^ ((ar >> 1) & 3)) << 3)];
            }
            if (pf) stage(t + 1, 1, kk);
            if (kk == 0) {
                if (pf) asm volatile("s_waitcnt vmcnt(4)" ::: "memory");
                else    asm volatile("s_waitcnt vmcnt(0)" ::: "memory");
            } else if (pf) {
                asm volatile("s_waitcnt vmcnt(4)" ::: "memory");
            }
            __builtin_amdgcn_s_barrier();
            asm volatile("s_waitcnt lgkmcnt(0)" ::: "memory");
            __builtin_amdgcn_s_setprio(1);
#pragma unroll
            for (int i = 0; i < 4; ++i)
#pragma unroll
                for (int j = 0; j < 4; ++j)
                    acc[4 + i][j] = __builtin_amdgcn_mfma_f32_16x16x32_bf16(af[i], bf[j], acc[4 + i][j], 0, 0, 0);
            __builtin_amdgcn_s_setprio(0);
            __builtin_amdgcn_s_barrier();
        }
    }
}

#define EPI256_VARS                                           \
    const int lane = threadIdx.x & 63;                        \
    const int lr = lane & 15, quad = lane >> 4;               \
    const int wr = (threadIdx.x >> 8) & 1, wc = (threadIdx.x >> 6) & 3;

// ---------------- K1: Mt = Wk *NT* Wq ----------------
__global__ __launch_bounds__(256) void mt_mfma(const u16* __restrict__ Wkb, const u16* __restrict__ Wqb,
                                               u16* __restrict__ Mt)
{
    __shared__ u16 Sh[32768];
    const int m0 = blockIdx.y * 128, n0 = blockIdx.x * 128;
    floatx4 acc[4][4];
#pragma unroll
    for (int i = 0; i < 4; ++i)
#pragma unroll
        for (int j = 0; j < 4; ++j) acc[i][j] = (floatx4){0.f, 0.f, 0.f, 0.f};
    mfma_nt_128(Wkb, D_, Wqb, D_, m0, n0, D_, Sh, acc);

    EPI_VARS
#pragma unroll
    for (int i = 0; i < 4; ++i)
#pragma unroll
        for (int j = 0; j < 4; ++j)
#pragma unroll
            for (int r = 0; r < 4; ++r)
                Mt[(size_t)(m0 + wm + i * 16 + quad * 4 + r) * D_ + n0 + wn + j * 16 + lr] = f2bf(acc[i][j][r]);
}

// ---------------- K2+K3 merged on 256^2 core: 256 blocks = 1/CU (r7-verified, 41.1 us) ----------------
__global__ __launch_bounds__(512, 2) void yv_mfma(const u16* __restrict__ xb, const u16* __restrict__ Mt,
                                                  const u16* __restrict__ Wvt,
                                                  u16* __restrict__ Y, u16* __restrict__ Vt)
{
    __shared__ u16 Sh[65536];
    const int lid = xcd_chunk(blockIdx.x, 256);
    floatx4 acc[8][4];
#pragma unroll
    for (int i = 0; i < 8; ++i)
#pragma unroll
        for (int j = 0; j < 4; ++j) acc[i][j] = (floatx4){0.f, 0.f, 0.f, 0.f};

    if (lid < 128) {
        const int m0 = (lid >> 2) * 256, n0 = (lid & 3) * 256;
        mfma_nt_256(xb, D_, Mt, D_, m0, n0, D_, Sh, acc);
        EPI256_VARS
#pragma unroll
        for (int i = 0; i < 8; ++i)
#pragma unroll
            for (int j = 0; j < 4; ++j)
#pragma unroll
                for (int r = 0; r < 4; ++r)
                    Y[(size_t)(m0 + wr * 128 + i * 16 + quad * 4 + r) * D_ + n0 + wc * 64 + j * 16 + lr]
                        = f2bf(acc[i][j][r]);
    } else {
        const int v = lid - 128;
        const int b = v >> 5;
        const int mloc = ((v >> 2) & 7) * 256;
        const int n0 = (v & 3) * 256;
        const int m0 = b * S_ + mloc;
        u16* Vb = Vt + (size_t)b * D_ * S_;
        mfma_nt_256(xb, D_, Wvt, D_, m0, n0, D_, Sh, acc);
        EPI256_VARS
#pragma unroll
        for (int i = 0; i < 8; ++i)
#pragma unroll
            for (int j = 0; j < 4; ++j) {
                const int ee = n0 + wc * 64 + j * 16 + lr;
                const int s4 = mloc + wr * 128 + i * 16 + quad * 4;
                ushort4 o;
                o.x = f2bf(acc[i][j][0]); o.y = f2bf(acc[i][j][1]);
                o.z = f2bf(acc[i][j][2]); o.w = f2bf(acc[i][j][3]);
                *(ushort4*)&Vb[(size_t)ee * S_ + s4] = o;
            }
    }
}

// ---------------- K4: Sc, 128-granular causal triangle: 544 blocks (2.1/CU, r8-verified) ----------------
__global__ __launch_bounds__(512, 2) void scores_mfma(const u16* __restrict__ Y, const u16* __restrict__ xb,
                                                      u16* __restrict__ Sc)
{
    __shared__ u16 Sh[32768];
    const int lid = xcd_chunk(blockIdx.x, 544);
    const int b = lid / 136;
    const int t = lid - b * 136;
    int qt = (int)((sqrtf(8.0f * t + 1.0f) - 1.0f) * 0.5f);
    while ((qt + 1) * (qt + 2) / 2 <= t) ++qt;
    while (qt * (qt + 1) / 2 > t) --qt;
    const int kt = t - qt * (qt + 1) / 2;

    const u16* A  = Y  + (size_t)b * S_ * D_;
    const u16* Bp = xb + (size_t)b * S_ * D_;
    u16* Sb = Sc + (size_t)b * S_ * S_;
    const int m0 = qt * 128, n0 = kt * 128;
    floatx4 acc[2][4];
#pragma unroll
    for (int i = 0; i < 2; ++i)
#pragma unroll
        for (int j = 0; j < 4; ++j) acc[i][j] = (floatx4){0.f, 0.f, 0.f, 0.f};
    mfma_nt_128w8(A, D_, Bp, D_, m0, n0, D_, Sh, acc);

    EPIW8_VARS
#pragma unroll
    for (int i = 0; i < 2; ++i)
#pragma unroll
        for (int r = 0; r < 4; ++r) {
            const int grow = m0 + wm + i * 16 + quad * 4 + r;
#pragma unroll
            for (int j = 0; j < 4; ++j) {
                const int gcol = n0 + wn + j * 16 + lr;
                const float v = (gcol <= grow) ? acc[i][j][r] * SCALE : NEGINF;
                Sb[(size_t)grow * S_ + gcol] = f2bf(v);
            }
        }
}

// ---------------- K5: row softmax, wave-per-row (no LDS, butterfly shfl; r4-verified) ----------------
__global__ __launch_bounds__(256) void softmax_k(const u16* __restrict__ Sc, u16* __restrict__ P)
{
    const int row = blockIdx.x * 4 + (threadIdx.x >> 6);
    const int lane = threadIdx.x & 63;
    const int b = row >> 11, q = row & (S_ - 1);
    const int L = ((q >> 7) + 1) << 7;           // 128-granular causal span
    const u16* rp = Sc + ((size_t)b * S_ + q) * S_;
    u16* pp = P + ((size_t)b * S_ + q) * S_;

    float f[4][8];
    float lmax = -3.4e38f;
#pragma unroll
    for (int c = 0; c < 4; ++c) {
        const int i = c * 512 + lane * 8;
        if (i < L) {
            short8 v = *(const short8*)&rp[i];
#pragma unroll
            for (int k = 0; k < 8; ++k) { f[c][k] = bf2f((u16)v[k]); lmax = fmaxf(lmax, f[c][k]); }
        }
    }
#pragma unroll
    for (int off = 32; off; off >>= 1) lmax = fmaxf(lmax, __shfl_xor(lmax, off, 64));

    float lsum = 0.f;
#pragma unroll
    for (int c = 0; c < 4; ++c) {
        const int i = c * 512 + lane * 8;
        if (i < L) {
#pragma unroll
            for (int k = 0; k < 8; ++k) { f[c][k] = __expf(f[c][k] - lmax); lsum += f[c][k]; }
        }
    }
#pragma unroll
    for (int off = 32; off; off >>= 1) lsum += __shfl_xor(lsum, off, 64);
    const float inv = 1.0f / lsum;

#pragma unroll
    for (int c = 0; c < 4; ++c) {
        const int i = c * 512 + lane * 8;
        if (i < L) {
            short8 o;
#pragma unroll
            for (int k = 0; k < 8; ++k) o[k] = (short)f2bf(f[c][k] * inv);
            *(short8*)&pp[i] = o;
        }
    }
}

// ---------------- K6: O = P Vt^T: 512 blocks (2/CU co-res), balanced qt ordering (r8-verified) ----------------
// lid = s*32 + (b*8+et); a CU's two blocks are lids (j, j+32) -> consecutive s.
// qt(2m)=m, qt(2m+1)=15-m: any consecutive-s pair sums to 17-18 K-tiles.
__global__ __launch_bounds__(512, 2) void pv_mfma(const u16* __restrict__ P, const u16* __restrict__ Vt,
                                                  float* __restrict__ O)
{
    __shared__ u16 Sh[32768];
    const int lid = xcd_chunk(blockIdx.x, 512);
    const int s  = lid >> 5;                   // 0..15
    const int be = lid & 31;
    const int b  = be >> 3, et = be & 7;
    const int qt = (s & 1) ? 15 - (s >> 1) : (s >> 1);
    const int m0 = qt * 128, n0 = et * 128;
    const int kext = (qt + 1) * 128;
    const u16* A  = P  + (size_t)b * S_ * S_;
    const u16* Bp = Vt + (size_t)b * D_ * S_;

    floatx4 acc[2][4];
#pragma unroll
    for (int i = 0; i < 2; ++i)
#pragma unroll
        for (int j = 0; j < 4; ++j) acc[i][j] = (floatx4){0.f, 0.f, 0.f, 0.f};
    mfma_nt_128w8(A, S_, Bp, S_, m0, n0, kext, Sh, acc);

    EPIW8_VARS
#pragma unroll
    for (int i = 0; i < 2; ++i)
#pragma unroll
        for (int r = 0; r < 4; ++r) {
            const int grow = m0 + wm + i * 16 + quad * 4 + r;
#pragma unroll
            for (int j = 0; j < 4; ++j)
                O[((size_t)b * S_ + grow) * D_ + n0 + wn + j * 16 + lr] = acc[i][j][r];
        }
}

extern "C" void kernel_launch(void* const* d_in, const int* in_sizes, int n_in,
                              void* d_out, int out_size, void* d_ws, size_t ws_size,
                              hipStream_t stream) {
    const float* x  = (const float*)d_in[0];
    const float* Wq = (const float*)d_in[1];
    const float* Wk = (const float*)d_in[2];
    const float* Wv = (const float*)d_in[3];
    float* out = (float*)d_out;
    char* w = (char*)d_ws;

    u16* xb  = (u16*)(w);                    // 16.8 MB
    u16* Wqb = (u16*)(w + 16777216);         //  2 MB
    u16* Wkb = (u16*)(w + 18874368);         //  2 MB
    u16* Wvt = (u16*)(w + 20971520);         //  2 MB
    u16* Mt  = (u16*)(w + 23068672);         //  2 MB
    u16* Y   = (u16*)(w + 25165824);         // 16.8 MB
    u16* Vt  = (u16*)(w + 41943040);         // 16.8 MB
    u16* Sc  = (u16*)(w + 58720256);         // 33.5 MB
    u16* P   = (u16*)(w + 92274688);         // 33.5 MB

    cast_fused <<<dim3(6144),   256, 0, stream>>>(x, Wq, Wk, Wv, xb, Wqb, Wkb, Wvt);
    mt_mfma    <<<dim3(8, 8),   256, 0, stream>>>(Wkb, Wqb, Mt);
    yv_mfma    <<<dim3(256),    512, 0, stream>>>(xb, Mt, Wvt, Y, Vt);
    scores_mfma<<<dim3(544),    512, 0, stream>>>(Y, xb, Sc);
    softmax_k  <<<dim3(N_/4),   256, 0, stream>>>(Sc, P);
    pv_mfma    <<<dim3(512),    512, 0, stream>>>(P, Vt, out);
}

// Round 11
// 208.732 us; speedup vs baseline: 1.1862x; 1.0116x over previous
//
#include <hip/hip_runtime.h>

#define B_  4
#define S_  2048
#define D_  1024
#define N_  (B_*S_)
#define SCALE 0.03125f
#define NEGINF (-3.0e38f)

typedef unsigned short u16;
typedef __attribute__((ext_vector_type(8))) short short8;
typedef __attribute__((ext_vector_type(4))) float floatx4;

__device__ __forceinline__ u16 f2bf(float f) {           // RNE float->bf16
    unsigned int u = __float_as_uint(f);
    u += 0x7FFFu + ((u >> 16) & 1u);
    return (u16)(u >> 16);
}
__device__ __forceinline__ float bf2f(u16 h) {
    return __uint_as_float((unsigned int)h << 16);
}

__device__ __forceinline__ void gl_lds16(const void* g, void* l) {
    __builtin_amdgcn_global_load_lds(
        (const __attribute__((address_space(1))) unsigned int*)g,
        (__attribute__((address_space(3))) unsigned int*)l, 16, 0, 0);
}

// bijective chunked XCD swizzle (nwg % 8 == 0)
__device__ __forceinline__ int xcd_chunk(int bid, int nwg) {
    return (bid & 7) * (nwg >> 3) + (bid >> 3);
}

// ---------------- fused casts ----------------
__global__ __launch_bounds__(256) void cast_fused(const float* __restrict__ x,
                                                  const float* __restrict__ Wq, const float* __restrict__ Wk,
                                                  const float* __restrict__ Wv,
                                                  u16* __restrict__ xb, u16* __restrict__ Wqb,
                                                  u16* __restrict__ Wkb, u16* __restrict__ Wvt) {
    __shared__ float t[32][33];
    const int blk = blockIdx.x;
    if (blk < 5120) {
        const float* src; u16* dst; size_t i;
        if (blk < 4096)      { src = x;  dst = xb;  i = (size_t)blk * 2048; }
        else if (blk < 4608) { src = Wq; dst = Wqb; i = (size_t)(blk - 4096) * 2048; }
        else                 { src = Wk; dst = Wkb; i = (size_t)(blk - 4608) * 2048; }
        i += (size_t)threadIdx.x * 8;
        float4 a = *(const float4*)&src[i];
        float4 b = *(const float4*)&src[i + 4];
        short8 o;
        o[0]=f2bf(a.x); o[1]=f2bf(a.y); o[2]=f2bf(a.z); o[3]=f2bf(a.w);
        o[4]=f2bf(b.x); o[5]=f2bf(b.y); o[6]=f2bf(b.z); o[7]=f2bf(b.w);
        *(short8*)&dst[i] = o;
    } else {
        const int tb = blk - 5120;                 // 0..1023
        const int c = threadIdx.x & 31, r0 = threadIdx.x >> 5;
        const int i0 = (tb >> 5) * 32, j0 = (tb & 31) * 32;
#pragma unroll
        for (int rr = 0; rr < 4; ++rr)
            t[r0 + rr * 8][c] = Wv[(size_t)(i0 + r0 + rr * 8) * D_ + j0 + c];
        __syncthreads();
#pragma unroll
        for (int rr = 0; rr < 4; ++rr)
            Wvt[(size_t)(j0 + r0 + rr * 8) * D_ + i0 + c] = f2bf(t[c][r0 + rr * 8]);
    }
}

// =====================================================================================
// LDS layout (all cores): per buffer, per matrix, two k-half planes [kk][row][32].
// Within a row, 4 slots of 8 bf16; slot holds global k-octet (slot ^ ((row>>1)&3)).
// Swizzle applied on the GLOBAL source (gl_lds dest is linear) and on the ds_read addr.
// Chunks staged in consumption order; counted vmcnt confirms exactly the half-tile
// about to be read, never draining the prefetch stream to 0 mid-loop.
// =====================================================================================

// ================= 128x128 core: 4 waves (256 thr), 2-phase, counted vmcnt =========
__device__ __forceinline__ void mfma_nt_128(const u16* __restrict__ A, int lda,
                                            const u16* __restrict__ Bp, int ldb,
                                            int m0, int n0, int kext,
                                            u16* Sh, floatx4 acc[4][4])
{
    const int tid  = threadIdx.x;          // 0..255
    const int lane = tid & 63;
    const int lr   = lane & 15, quad = lane >> 4;
    const int wm   = ((tid >> 6) & 1) * 64, wn = (tid >> 7) * 64;
    const int nt   = kext >> 6;

    auto stage1 = [&](int t, int h) {      // 1 gl_lds / thread, 64 rows x 32 cols
        const int kk = h >> 2, mat = (h >> 1) & 1, half = h & 1;
        const int idx = tid * 8;           // 0..2047
        const int row = half * 64 + (idx >> 5);
        const int s   = (idx & 31) >> 3;
        const int gk  = (t << 6) + kk * 32 + ((s ^ ((row >> 1) & 3)) << 3);
        u16* dst = Sh + (t & 1) * 16384 + mat * 8192 + kk * 4096 + half * 2048 + idx;
        const u16* src = mat ? &Bp[(size_t)(n0 + row) * ldb + gk]
                             : &A [(size_t)(m0 + row) * lda + gk];
        gl_lds16(src, dst);
    };

#pragma unroll
    for (int h = 0; h < 8; ++h) stage1(0, h);              // prologue: tile 0

    for (int t = 0; t < nt; ++t) {
        const u16* buf = Sh + (t & 1) * 16384;
        const bool pf = (t + 1 < nt);
#pragma unroll
        for (int p = 0; p < 2; ++p) {                      // p = kk
            if (pf) {
#pragma unroll
                for (int h = 0; h < 4; ++h) stage1(t + 1, p * 4 + h);
                asm volatile("s_waitcnt vmcnt(8)" ::: "memory");
            } else if (p == 0) {
                asm volatile("s_waitcnt vmcnt(4)" ::: "memory");
            } else {
                asm volatile("s_waitcnt vmcnt(0)" ::: "memory");
            }
            __builtin_amdgcn_s_barrier();

            short8 af[4], bf[4];
#pragma unroll
            for (int i = 0; i < 4; ++i) {
                const int ar = wm + i * 16 + lr;
                af[i] = *(const short8*)&buf[p * 4096 + ar * 32 + ((quad ^ ((ar >> 1) & 3)) << 3)];
                const int br = wn + i * 16 + lr;
                bf[i] = *(const short8*)&buf[8192 + p * 4096 + br * 32 + ((quad ^ ((br >> 1) & 3)) << 3)];
            }
            asm volatile("s_waitcnt lgkmcnt(0)" ::: "memory");
            __builtin_amdgcn_s_setprio(1);
#pragma unroll
            for (int i = 0; i < 4; ++i)
#pragma unroll
                for (int j = 0; j < 4; ++j)
                    acc[i][j] = __builtin_amdgcn_mfma_f32_16x16x32_bf16(af[i], bf[j], acc[i][j], 0, 0, 0);
            __builtin_amdgcn_s_setprio(0);
            __builtin_amdgcn_s_barrier();
        }
    }
}

#define EPI_VARS                                              \
    const int lane = threadIdx.x & 63;                        \
    const int lr = lane & 15, quad = lane >> 4;               \
    const int wm = ((threadIdx.x >> 6) & 1) * 64, wn = (threadIdx.x >> 7) * 64;

// ========== 128x128 core, 8 waves (512 thr): wave tile 32x64, 2-phase, counted vmcnt ====
__device__ __forceinline__ void mfma_nt_128w8(const u16* __restrict__ A, int lda,
                                              const u16* __restrict__ Bp, int ldb,
                                              int m0, int n0, int kext,
                                              u16* Sh, floatx4 acc[2][4])
{
    const int tid  = threadIdx.x;          // 0..511
    const int lane = tid & 63;
    const int lr   = lane & 15, quad = lane >> 4;
    const int wid  = tid >> 6;             // 0..7
    const int wm   = (wid >> 1) * 32;      // 0,32,64,96
    const int wn   = (wid & 1) * 64;       // 0,64
    const int nt   = kext >> 6;

    auto stage1 = [&](int t, int h) {      // h = kk*2 + mat; 1 gl_lds / thread
        const int kk = h >> 1, mat = h & 1;
        const int idx = tid * 8;           // 0..4095 -> full 128x32 plane
        const int row = idx >> 5;
        const int s   = (idx & 31) >> 3;
        const int gk  = (t << 6) + kk * 32 + ((s ^ ((row >> 1) & 3)) << 3);
        u16* dst = Sh + (t & 1) * 16384 + mat * 8192 + kk * 4096 + idx;
        const u16* src = mat ? &Bp[(size_t)(n0 + row) * ldb + gk]
                             : &A [(size_t)(m0 + row) * lda + gk];
        gl_lds16(src, dst);
    };

#pragma unroll
    for (int h = 0; h < 4; ++h) stage1(0, h);              // prologue: tile 0

    for (int t = 0; t < nt; ++t) {
        const u16* buf = Sh + (t & 1) * 16384;
        const bool pf = (t + 1 < nt);
#pragma unroll
        for (int p = 0; p < 2; ++p) {                      // p = kk
            if (pf) {
                stage1(t + 1, p * 2); stage1(t + 1, p * 2 + 1);
                asm volatile("s_waitcnt vmcnt(4)" ::: "memory");   // t's kk=p planes done
            } else if (p == 0) {
                asm volatile("s_waitcnt vmcnt(2)" ::: "memory");
            } else {
                asm volatile("s_waitcnt vmcnt(0)" ::: "memory");
            }
            __builtin_amdgcn_s_barrier();

            short8 af[2], bf[4];
#pragma unroll
            for (int i = 0; i < 2; ++i) {
                const int ar = wm + i * 16 + lr;
                af[i] = *(const short8*)&buf[p * 4096 + ar * 32 + ((quad ^ ((ar >> 1) & 3)) << 3)];
            }
#pragma unroll
            for (int j = 0; j < 4; ++j) {
                const int br = wn + j * 16 + lr;
                bf[j] = *(const short8*)&buf[8192 + p * 4096 + br * 32 + ((quad ^ ((br >> 1) & 3)) << 3)];
            }
            asm volatile("s_waitcnt lgkmcnt(0)" ::: "memory");
            __builtin_amdgcn_s_setprio(1);
#pragma unroll
            for (int i = 0; i < 2; ++i)
#pragma unroll
                for (int j = 0; j < 4; ++j)
                    acc[i][j] = __builtin_amdgcn_mfma_f32_16x16x32_bf16(af[i], bf[j], acc[i][j], 0, 0, 0);
            __builtin_amdgcn_s_setprio(0);
            __builtin_amdgcn_s_barrier();
        }
    }
}

// ================= 256x256 core: 8 waves (2Mx4N), 4-phase (kk x mh), counted vmcnt ====
__device__ __forceinline__ void mfma_nt_256(const u16* __restrict__ A, int lda,
                                            const u16* __restrict__ Bp, int ldb,
                                            int m0, int n0, int kext,
                                            u16* Sh, floatx4 acc[8][4])
{
    const int tid  = threadIdx.x;          // 0..511
    const int lane = tid & 63;
    const int lr   = lane & 15, quad = lane >> 4;
    const int wr   = (tid >> 8) & 1, wc = (tid >> 6) & 3;
    const int nt   = kext >> 6;

    auto stage1 = [&](int t, int h) {      // 1 gl_lds / thread, 128 rows x 32 cols
        const int kk = h >> 2, mat = (h >> 1) & 1, half = h & 1;
        const int idx = tid * 8;           // 0..4095
        const int row = half * 128 + (idx >> 5);
        const int s   = (idx & 31) >> 3;
        const int gk  = (t << 6) + kk * 32 + ((s ^ ((row >> 1) & 3)) << 3);
        u16* dst = Sh + (t & 1) * 32768 + mat * 16384 + kk * 8192 + half * 4096 + idx;
        const u16* src = mat ? &Bp[(size_t)(n0 + row) * ldb + gk]
                             : &A [(size_t)(m0 + row) * lda + gk];
        gl_lds16(src, dst);
    };

#pragma unroll
    for (int h = 0; h < 8; ++h) stage1(0, h);              // prologue: tile 0

    for (int t = 0; t < nt; ++t) {
        const u16* buf = Sh + (t & 1) * 32768;
        const bool pf = (t + 1 < nt);
        short8 af[4], bf[4];

        // ---- phase 0: (kk0, mh0)
        if (pf) { stage1(t + 1, 0); stage1(t + 1, 1);
                  asm volatile("s_waitcnt vmcnt(6)" ::: "memory"); }
        else      asm volatile("s_waitcnt vmcnt(4)" ::: "memory");
        __builtin_amdgcn_s_barrier();
#pragma unroll
        for (int i = 0; i < 4; ++i) {
            const int ar = wr * 128 + i * 16 + lr;
            af[i] = *(const short8*)&buf[ar * 32 + ((quad ^ ((ar >> 1) & 3)) << 3)];
            const int br = wc * 64 + i * 16 + lr;
            bf[i] = *(const short8*)&buf[16384 + br * 32 + ((quad ^ ((br >> 1) & 3)) << 3)];
        }
        asm volatile("s_waitcnt lgkmcnt(0)" ::: "memory");
        __builtin_amdgcn_s_setprio(1);
#pragma unroll
        for (int i = 0; i < 4; ++i)
#pragma unroll
            for (int j = 0; j < 4; ++j)
                acc[i][j] = __builtin_amdgcn_mfma_f32_16x16x32_bf16(af[i], bf[j], acc[i][j], 0, 0, 0);
        __builtin_amdgcn_s_setprio(0);
        __builtin_amdgcn_s_barrier();

        // ---- phase 1: (kk0, mh1) -- bf reused
#pragma unroll
        for (int i = 0; i < 4; ++i) {
            const int ar = wr * 128 + 64 + i * 16 + lr;
            af[i] = *(const short8*)&buf[ar * 32 + ((quad ^ ((ar >> 1) & 3)) << 3)];
        }
        if (pf) { stage1(t + 1, 2); stage1(t + 1, 3); }
        __builtin_amdgcn_s_barrier();
        asm volatile("s_waitcnt lgkmcnt(0)" ::: "memory");
        __builtin_amdgcn_s_setprio(1);
#pragma unroll
        for (int i = 0; i < 4; ++i)
#pragma unroll
            for (int j = 0; j < 4; ++j)
                acc[4 + i][j] = __builtin_amdgcn_mfma_f32_16x16x32_bf16(af[i], bf[j], acc[4 + i][j], 0, 0, 0);
        __builtin_amdgcn_s_setprio(0);
        __builtin_amdgcn_s_barrier();

        // ---- phase 2: (kk1, mh0)
        if (pf) { stage1(t + 1, 4); stage1(t + 1, 5);
                  asm volatile("s_waitcnt vmcnt(6)" ::: "memory"); }
        else      asm volatile("s_waitcnt vmcnt(0)" ::: "memory");
        __builtin_amdgcn_s_barrier();
#pragma unroll
        for (int i = 0; i < 4; ++i) {
            const int ar = wr * 128 + i * 16 + lr;
            af[i] = *(const short8*)&buf[8192 + ar * 32 + ((quad ^ ((ar >> 1) & 3)) << 3)];
            const int br = wc * 64 + i * 16 + lr;
            bf[i] = *(const short8*)&buf[24576 + br * 32 + ((quad ^ ((br >> 1) & 3)) << 3)];
        }
        asm volatile("s_waitcnt lgkmcnt(0)" ::: "memory");
        __builtin_amdgcn_s_setprio(1);
#pragma unroll
        for (int i = 0; i < 4; ++i)
#pragma unroll
            for (int j = 0; j < 4; ++j)
                acc[i][j] = __builtin_amdgcn_mfma_f32_16x16x32_bf16(af[i], bf[j], acc[i][j], 0, 0, 0);
        __builtin_amdgcn_s_setprio(0);
        __builtin_amdgcn_s_barrier();

        // ---- phase 3: (kk1, mh1)
#pragma unroll
        for (int i = 0; i < 4; ++i) {
            const int ar = wr * 128 + 64 + i * 16 + lr;
            af[i] = *(const short8*)&buf[8192 + ar * 32 + ((quad ^ ((ar >> 1) & 3)) << 3)];
        }
        if (pf) { stage1(t + 1, 6); stage1(t + 1, 7); }
        __builtin_amdgcn_s_barrier();
        asm volatile("s_waitcnt lgkmcnt(0)" ::: "memory");
        __builtin_amdgcn_s_setprio(1);
#pragma unroll
        for (int i = 0; i < 4; ++i)
#pragma unroll
            for (int j = 0; j < 4; ++j)
                acc[4 + i][j] = __builtin_amdgcn_mfma_f32_16x16x32_bf16(af[i], bf[j], acc[4 + i][j], 0, 0, 0);
        __builtin_amdgcn_s_setprio(0);
        __builtin_amdgcn_s_barrier();
    }
}

#define EPI256_VARS                                           \
    const int lane = threadIdx.x & 63;                        \
    const int lr = lane & 15, quad = lane >> 4;               \
    const int wr = (threadIdx.x >> 8) & 1, wc = (threadIdx.x >> 6) & 3;

// ---------------- K1: Mt = Wk *NT* Wq ----------------
__global__ __launch_bounds__(256) void mt_mfma(const u16* __restrict__ Wkb, const u16* __restrict__ Wqb,
                                               u16* __restrict__ Mt)
{
    __shared__ u16 Sh[32768];
    const int m0 = blockIdx.y * 128, n0 = blockIdx.x * 128;
    floatx4 acc[4][4];
#pragma unroll
    for (int i = 0; i < 4; ++i)
#pragma unroll
        for (int j = 0; j < 4; ++j) acc[i][j] = (floatx4){0.f, 0.f, 0.f, 0.f};
    mfma_nt_128(Wkb, D_, Wqb, D_, m0, n0, D_, Sh, acc);

    EPI_VARS
#pragma unroll
    for (int i = 0; i < 4; ++i)
#pragma unroll
        for (int j = 0; j < 4; ++j)
#pragma unroll
            for (int r = 0; r < 4; ++r)
                Mt[(size_t)(m0 + wm + i * 16 + quad * 4 + r) * D_ + n0 + wn + j * 16 + lr] = f2bf(acc[i][j][r]);
}

// ---------------- K2+K3 merged on 256^2 core: 256 blocks = 1/CU ----------------
__global__ __launch_bounds__(512, 2) void yv_mfma(const u16* __restrict__ xb, const u16* __restrict__ Mt,
                                                  const u16* __restrict__ Wvt,
                                                  u16* __restrict__ Y, u16* __restrict__ Vt)
{
    __shared__ u16 Sh[65536];                            // 128 KiB
    const int lid = xcd_chunk(blockIdx.x, 256);
    floatx4 acc[8][4];
#pragma unroll
    for (int i = 0; i < 8; ++i)
#pragma unroll
        for (int j = 0; j < 4; ++j) acc[i][j] = (floatx4){0.f, 0.f, 0.f, 0.f};

    if (lid < 128) {
        const int m0 = (lid >> 2) * 256, n0 = (lid & 3) * 256;
        mfma_nt_256(xb, D_, Mt, D_, m0, n0, D_, Sh, acc);
        EPI256_VARS
#pragma unroll
        for (int i = 0; i < 8; ++i)
#pragma unroll
            for (int j = 0; j < 4; ++j)
#pragma unroll
                for (int r = 0; r < 4; ++r)
                    Y[(size_t)(m0 + wr * 128 + i * 16 + quad * 4 + r) * D_ + n0 + wc * 64 + j * 16 + lr]
                        = f2bf(acc[i][j][r]);
    } else {
        const int v = lid - 128;
        const int b = v >> 5;
        const int mloc = ((v >> 2) & 7) * 256;
        const int n0 = (v & 3) * 256;
        const int m0 = b * S_ + mloc;
        u16* Vb = Vt + (size_t)b * D_ * S_;
        mfma_nt_256(xb, D_, Wvt, D_, m0, n0, D_, Sh, acc);
        EPI256_VARS
#pragma unroll
        for (int i = 0; i < 8; ++i)
#pragma unroll
            for (int j = 0; j < 4; ++j) {
                const int ee = n0 + wc * 64 + j * 16 + lr;
                const int s4 = mloc + wr * 128 + i * 16 + quad * 4;
                ushort4 o;
                o.x = f2bf(acc[i][j][0]); o.y = f2bf(acc[i][j][1]);
                o.z = f2bf(acc[i][j][2]); o.w = f2bf(acc[i][j][3]);
                *(ushort4*)&Vb[(size_t)ee * S_ + s4] = o;
            }
    }
}

// ---------------- K4: Sc = bf16(scale * Y x^T), 256-granular causal triangle ----------------
__global__ __launch_bounds__(512, 2) void scores_mfma(const u16* __restrict__ Y, const u16* __restrict__ xb,
                                                      u16* __restrict__ Sc)
{
    __shared__ u16 Sh[65536];
    const int lid = xcd_chunk(blockIdx.x, 144);
    const int b = lid / 36;
    const int t = lid - b * 36;
    int qt = 0;
    while ((qt + 1) * (qt + 2) / 2 <= t) ++qt;
    const int kt = t - qt * (qt + 1) / 2;

    const u16* A  = Y  + (size_t)b * S_ * D_;
    const u16* Bp = xb + (size_t)b * S_ * D_;
    u16* Sb = Sc + (size_t)b * S_ * S_;
    const int m0 = qt * 256, n0 = kt * 256;
    floatx4 acc[8][4];
#pragma unroll
    for (int i = 0; i < 8; ++i)
#pragma unroll
        for (int j = 0; j < 4; ++j) acc[i][j] = (floatx4){0.f, 0.f, 0.f, 0.f};
    mfma_nt_256(A, D_, Bp, D_, m0, n0, D_, Sh, acc);

    EPI256_VARS
#pragma unroll
    for (int i = 0; i < 8; ++i)
#pragma unroll
        for (int r = 0; r < 4; ++r) {
            const int grow = m0 + wr * 128 + i * 16 + quad * 4 + r;
#pragma unroll
            for (int j = 0; j < 4; ++j) {
                const int gcol = n0 + wc * 64 + j * 16 + lr;
                const float v = (gcol <= grow) ? acc[i][j][r] * SCALE : NEGINF;
                Sb[(size_t)grow * S_ + gcol] = f2bf(v);
            }
        }
}

// ---------------- K5: row softmax, wave-per-row (no LDS, butterfly shfl) ----------------
__global__ __launch_bounds__(256) void softmax_k(const u16* __restrict__ Sc, u16* __restrict__ P)
{
    const int row = blockIdx.x * 4 + (threadIdx.x >> 6);
    const int lane = threadIdx.x & 63;
    const int b = row >> 11, q = row & (S_ - 1);
    const int L = ((q >> 7) + 1) << 7;           // 128-granular causal span
    const u16* rp = Sc + ((size_t)b * S_ + q) * S_;
    u16* pp = P + ((size_t)b * S_ + q) * S_;

    float f[4][8];
    float lmax = -3.4e38f;
#pragma unroll
    for (int c = 0; c < 4; ++c) {
        const int i = c * 512 + lane * 8;
        if (i < L) {
            short8 v = *(const short8*)&rp[i];
#pragma unroll
            for (int k = 0; k < 8; ++k) { f[c][k] = bf2f((u16)v[k]); lmax = fmaxf(lmax, f[c][k]); }
        }
    }
#pragma unroll
    for (int off = 32; off; off >>= 1) lmax = fmaxf(lmax, __shfl_xor(lmax, off, 64));

    float lsum = 0.f;
#pragma unroll
    for (int c = 0; c < 4; ++c) {
        const int i = c * 512 + lane * 8;
        if (i < L) {
#pragma unroll
            for (int k = 0; k < 8; ++k) { f[c][k] = __expf(f[c][k] - lmax); lsum += f[c][k]; }
        }
    }
#pragma unroll
    for (int off = 32; off; off >>= 1) lsum += __shfl_xor(lsum, off, 64);
    const float inv = 1.0f / lsum;

#pragma unroll
    for (int c = 0; c < 4; ++c) {
        const int i = c * 512 + lane * 8;
        if (i < L) {
            short8 o;
#pragma unroll
            for (int k = 0; k < 8; ++k) o[k] = (short)f2bf(f[c][k] * inv);
            *(short8*)&pp[i] = o;
        }
    }
}

// ---------------- K6: O = P Vt^T, qt-paired (perfect balance: 17 K-tiles/block) ----------------
// 256 blocks (1/CU), 512 thr (8 waves). Block does qtA=pr and qtB=15-pr sequentially.
__device__ __forceinline__ void pv_epi(floatx4 acc[2][4], int b, int m0, int n0, float* __restrict__ O)
{
    const int lane = threadIdx.x & 63;
    const int lr = lane & 15, quad = lane >> 4;
    const int wid = threadIdx.x >> 6;
    const int wm = (wid >> 1) * 32, wn = (wid & 1) * 64;
#pragma unroll
    for (int i = 0; i < 2; ++i)
#pragma unroll
        for (int r = 0; r < 4; ++r) {
            const int grow = m0 + wm + i * 16 + quad * 4 + r;
#pragma unroll
            for (int j = 0; j < 4; ++j)
                O[((size_t)b * S_ + grow) * D_ + n0 + wn + j * 16 + lr] = acc[i][j][r];
        }
}

__global__ __launch_bounds__(512, 2) void pv_mfma(const u16* __restrict__ P, const u16* __restrict__ Vt,
                                                  float* __restrict__ O)
{
    __shared__ u16 Sh[32768];                  // 64 KiB: 2buf x (A 16KB + B 16KB)
    const int lid = xcd_chunk(blockIdx.x, 256);
    const int b  = lid >> 6;                   // 0..3
    const int et = (lid >> 3) & 7;             // 0..7
    const int pr = lid & 7;                    // 0..7
    const int n0 = et * 128;
    const u16* A  = P  + (size_t)b * S_ * S_;
    const u16* Bp = Vt + (size_t)b * D_ * S_;

    floatx4 acc[2][4];
    const int qtA = pr, qtB = 15 - pr;

#pragma unroll
    for (int i = 0; i < 2; ++i)
#pragma unroll
        for (int j = 0; j < 4; ++j) acc[i][j] = (floatx4){0.f, 0.f, 0.f, 0.f};
    mfma_nt_128w8(A, S_, Bp, S_, qtA * 128, n0, (qtA + 1) * 128, Sh, acc);
    pv_epi(acc, b, qtA * 128, n0, O);

#pragma unroll
    for (int i = 0; i < 2; ++i)
#pragma unroll
        for (int j = 0; j < 4; ++j) acc[i][j] = (floatx4){0.f, 0.f, 0.f, 0.f};
    mfma_nt_128w8(A, S_, Bp, S_, qtB * 128, n0, (qtB + 1) * 128, Sh, acc);
    pv_epi(acc, b, qtB * 128, n0, O);
}

extern "C" void kernel_launch(void* const* d_in, const int* in_sizes, int n_in,
                              void* d_out, int out_size, void* d_ws, size_t ws_size,
                              hipStream_t stream) {
    const float* x  = (const float*)d_in[0];
    const float* Wq = (const float*)d_in[1];
    const float* Wk = (const float*)d_in[2];
    const float* Wv = (const float*)d_in[3];
    float* out = (float*)d_out;
    char* w = (char*)d_ws;

    u16* xb  = (u16*)(w);                    // 16.8 MB
    u16* Wqb = (u16*)(w + 16777216);         //  2 MB
    u16* Wkb = (u16*)(w + 18874368);         //  2 MB
    u16* Wvt = (u16*)(w + 20971520);         //  2 MB
    u16* Mt  = (u16*)(w + 23068672);         //  2 MB
    u16* Y   = (u16*)(w + 25165824);         // 16.8 MB
    u16* Vt  = (u16*)(w + 41943040);         // 16.8 MB
    u16* Sc  = (u16*)(w + 58720256);         // 33.5 MB
    u16* P   = (u16*)(w + 92274688);         // 33.5 MB

    cast_fused <<<dim3(6144),   256, 0, stream>>>(x, Wq, Wk, Wv, xb, Wqb, Wkb, Wvt);
    mt_mfma    <<<dim3(8, 8),   256, 0, stream>>>(Wkb, Wqb, Mt);
    yv_mfma    <<<dim3(256),    512, 0, stream>>>(xb, Mt, Wvt, Y, Vt);
    scores_mfma<<<dim3(144),    512, 0, stream>>>(Y, xb, Sc);
    softmax_k  <<<dim3(N_/4),   256, 0, stream>>>(Sc, P);
    pv_mfma    <<<dim3(256),    512, 0, stream>>>(P, Vt, out);
}